// Round 1
// baseline (14019.420 us; speedup 1.0000x reference)
//
#include <hip/hip_runtime.h>

// GRU decoder with Bahdanau attention, B=32, T=64, O=E=384, H=768.
// Persistent cooperative kernel, 3 grid barriers per step.

#define DEVI static __device__ __forceinline__

constexpr int ATTN_OFF = 786432;

// ws offsets (floats)
constexpr int OFF_H    = 0;        // 2 x (32*768) h double buffer (b,k)
constexpr int OFF_U    = 49152;    // (b,k) 32*768
constexpr int OFF_GH   = 73728;    // (row,b) 2304*32
constexpr int OFF_GIE  = 147456;   // (row,b) 2304*32
constexpr int OFF_FE   = 221184;   // (row,b) 384*32
constexpr int OFF_GE   = 233472;   // (row,b) 768*32
constexpr int OFF_FP   = 258048;   // (row,b) 384*32
constexpr int OFF_CP   = 270336;   // (row,b) 768*32
constexpr int OFF_SC   = 294912;   // (b,t) 32*64  p=exp(s-M)
constexpr int OFF_PD   = 296960;   // (b,tc) 32*2
constexpr int OFF_PW   = 297024;   // (b*2+tc, o) 64*384
constexpr int OFF_CALL = 321600;   // c_all (t,b,k) 64*32*768
constexpr int OFF_HIST = 1894464;  // hist (t,b,o) 64*32*384
constexpr int OFF_GHM  = 2680896;  // Gh (768,768) = A_o F_h
constexpr int OFF_GWM  = 3270720;  // Gw (768,384) = A_o F_w
constexpr int OFF_GEM  = 3565632;  // Ge (768,384) = A_o F_e
constexpr int OFF_GB   = 3860544;  // 768 = A_o fc_b
constexpr int OFF_V1   = 3861312;  // M = sum|v|
constexpr int OFF_BAR  = 3861344;  // barrier, 1152 u32
// total 3862496 floats = 14.74 MiB of d_ws

DEVI float fast_tanh(float x) {
  float a = __builtin_fabsf(x);
  float e = __expf(-2.0f * a);
  float r = __fdividef(1.0f - e, 1.0f + e);
  return __builtin_copysignf(r, x);
}
DEVI float sigmoidf_(float x) {
  return __fdividef(1.0f, 1.0f + __expf(-x));
}

DEVI void gridbar(unsigned* bar) {
  __syncthreads();
  if (threadIdx.x == 0) {
    __threadfence();
    unsigned* super = bar + 1024;
    unsigned* gen   = bar + 1056;
    unsigned g = __hip_atomic_load(gen, __ATOMIC_RELAXED, __HIP_MEMORY_SCOPE_AGENT);
    int grp = (int)(blockIdx.x >> 3);  // 32 groups of 8 blocks
    unsigned a = __hip_atomic_fetch_add(bar + grp * 32, 1u, __ATOMIC_ACQ_REL, __HIP_MEMORY_SCOPE_AGENT);
    bool released = false;
    if (a == 7u) {
      __hip_atomic_store(bar + grp * 32, 0u, __ATOMIC_RELAXED, __HIP_MEMORY_SCOPE_AGENT);
      unsigned s = __hip_atomic_fetch_add(super, 1u, __ATOMIC_ACQ_REL, __HIP_MEMORY_SCOPE_AGENT);
      if (s == 31u) {
        __hip_atomic_store(super, 0u, __ATOMIC_RELAXED, __HIP_MEMORY_SCOPE_AGENT);
        __hip_atomic_fetch_add(gen, 1u, __ATOMIC_RELEASE, __HIP_MEMORY_SCOPE_AGENT);
        released = true;
      }
    }
    if (!released) {
      while (__hip_atomic_load(gen, __ATOMIC_ACQUIRE, __HIP_MEMORY_SCOPE_AGENT) == g) {
        __builtin_amdgcn_s_sleep(1);
      }
    }
    __threadfence();
  }
  __syncthreads();
}

// ---------- precompute kernel: Gh/Gw/Ge/gb ----------
__global__ __launch_bounds__(256) void kprepG(const float* __restrict__ attn_W,
                                              const float* __restrict__ fcW,
                                              const float* __restrict__ fcb,
                                              float* __restrict__ ws) {
  int bid = blockIdx.x, tid = threadIdx.x;
  if (bid < 288) {
    int rt = bid / 6, kt = bid % 6;
    int r0 = rt * 16;
    int kg = kt * 256 + tid;  // column in the 1536-wide combined space
    float acc[16];
#pragma unroll
    for (int q = 0; q < 16; ++q) acc[q] = 0.f;
    for (int o = 0; o < 384; ++o) {
      float f = fcW[o * 1536 + kg];
#pragma unroll
      for (int q = 0; q < 16; ++q)
        acc[q] = fmaf(attn_W[(r0 + q) * 1152 + 768 + o], f, acc[q]);
    }
#pragma unroll
    for (int q = 0; q < 16; ++q) {
      int r = r0 + q;
      if (kg < 768)       ws[OFF_GHM + r * 768 + kg] = acc[q];
      else if (kg < 1152) ws[OFF_GWM + r * 384 + (kg - 768)] = acc[q];
      else                ws[OFF_GEM + r * 384 + (kg - 1152)] = acc[q];
    }
  } else {
    // gb = A_o fc_b
    for (int r = tid; r < 768; r += 256) {
      float a = 0.f;
      for (int o = 0; o < 384; ++o) a = fmaf(attn_W[r * 1152 + 768 + o], fcb[o], a);
      ws[OFF_GB + r] = a;
    }
  }
}

// ---------- prep kernel: zeros, h copy, M, barrier ----------
__global__ __launch_bounds__(256) void kprep0(const float* __restrict__ hidden,
                                              const float* __restrict__ vW,
                                              float* __restrict__ ws) {
  int bid = blockIdx.x, tid = threadIdx.x;
  int gtid = bid * 256 + tid;
  if (gtid < 24576) {
    ws[OFF_CALL + gtid] = 0.f;       // c_all[0] = 0
    ws[OFF_H + gtid] = hidden[gtid]; // h_0
  } else if (gtid < 36864) {
    ws[OFF_HIST + (gtid - 24576)] = 0.f;  // hist[0] = 0
  }
  if (gtid < 1152) ((unsigned*)(ws + OFF_BAR))[gtid] = 0u;
  if (bid == 0) {
    __shared__ float vred[256];
    float a = 0.f;
    for (int k = tid; k < 768; k += 256) a += __builtin_fabsf(vW[k]);
    vred[tid] = a;
    __syncthreads();
    for (int s2 = 128; s2 > 0; s2 >>= 1) {
      if (tid < s2) vred[tid] += vred[tid + s2];
      __syncthreads();
    }
    if (tid == 0) ws[OFF_V1] = vred[0];
  }
}

// ---------- main persistent cooperative kernel ----------
__global__ void __launch_bounds__(1024)
kmain(const int* __restrict__ target, const float* __restrict__ emb,
      const float* __restrict__ attn_W, const float* __restrict__ attn_b,
      const float* __restrict__ vW,
      const float* __restrict__ Wih, const float* __restrict__ Whh,
      const float* __restrict__ bih, const float* __restrict__ bhh,
      const float* __restrict__ fcW, const float* __restrict__ fcb,
      float* __restrict__ outp, float* __restrict__ ws) {
  const int bid = blockIdx.x, tid = threadIdx.x;
  const int wv = tid >> 6, lane = tid & 63;
  const int b32 = lane & 31, kh = lane >> 5;
  const int wg = bid * 16 + wv;  // 0..4095
  unsigned* bar = (unsigned*)(ws + OFF_BAR);

  __shared__ float part_[2048];        // 4 groups * 4 kq * 4 rows * 32 b
  __shared__ float w_lds[32 * 388];    // context w, padded stride
  __shared__ float giw_lds[288];       // 9 rows * 32 b
  __shared__ float D_lds[32];          // 1/D per b
  __shared__ float sred[32];
  __shared__ float pv2[32];
  __shared__ float pwred_[384];

  const float Mv = ws[OFF_V1];

  for (int i = 0; i < 64; ++i) {
    // ================= Phase A: u, gh, c_i, out_{i-1} (4224 rows, K=768) ==========
    {
      const float* hcur = ws + OFF_H + (i & 1) * 24576;
      int gb = (bid * 1056) >> 8;
      int geE = ((bid + 1) * 1056) >> 8;
      int gl = wv >> 2, kq = wv & 3;
      int nsw = (geE - gb + 3) >> 2;
      for (int sw = 0; sw < nsw; ++sw) {
        int g = gb + sw * 4 + gl;
        if (g < geE && !(i == 0 && g >= 768)) {
          const float* Wb; int ld;
          if (g < 192)      { Wb = attn_W + (g * 4) * 1152;               ld = 1152; }
          else if (g < 768) { Wb = Whh + ((g - 192) * 4) * 768;           ld = 768;  }
          else if (g < 960) { Wb = ws + OFF_GHM + ((g - 768) * 4) * 768;  ld = 768;  }
          else              { Wb = fcW + ((g - 960) * 4) * 1536;          ld = 1536; }
          const float* xp = hcur + b32 * 768 + kq * 192 + kh * 96;
          const float* wp = Wb + kq * 192 + kh * 96;
          float a0 = 0.f, a1 = 0.f, a2 = 0.f, a3 = 0.f;
#pragma unroll 6
          for (int q = 0; q < 24; ++q) {
            float4 xv = ((const float4*)xp)[q];
            float4 w0 = ((const float4*)(wp))[q];
            float4 w1 = ((const float4*)(wp + ld))[q];
            float4 w2 = ((const float4*)(wp + 2 * ld))[q];
            float4 w3 = ((const float4*)(wp + 3 * ld))[q];
            a0 = fmaf(w0.x, xv.x, a0); a0 = fmaf(w0.y, xv.y, a0);
            a0 = fmaf(w0.z, xv.z, a0); a0 = fmaf(w0.w, xv.w, a0);
            a1 = fmaf(w1.x, xv.x, a1); a1 = fmaf(w1.y, xv.y, a1);
            a1 = fmaf(w1.z, xv.z, a1); a1 = fmaf(w1.w, xv.w, a1);
            a2 = fmaf(w2.x, xv.x, a2); a2 = fmaf(w2.y, xv.y, a2);
            a2 = fmaf(w2.z, xv.z, a2); a2 = fmaf(w2.w, xv.w, a2);
            a3 = fmaf(w3.x, xv.x, a3); a3 = fmaf(w3.y, xv.y, a3);
            a3 = fmaf(w3.z, xv.z, a3); a3 = fmaf(w3.w, xv.w, a3);
          }
          a0 += __shfl_xor(a0, 32); a1 += __shfl_xor(a1, 32);
          a2 += __shfl_xor(a2, 32); a3 += __shfl_xor(a3, 32);
          if (kh == 0) {
            float* pp = part_ + ((gl * 4 + kq) * 4) * 32 + b32;
            pp[0] = a0; pp[32] = a1; pp[64] = a2; pp[96] = a3;
          }
        }
        __syncthreads();
        if (tid < 512) {
          int gl2 = tid >> 7, rr = (tid >> 5) & 3, bb = tid & 31;
          int g2 = gb + sw * 4 + gl2;
          if (g2 < geE && !(i == 0 && g2 >= 768)) {
            float sum = part_[((gl2 * 4 + 0) * 4 + rr) * 32 + bb]
                      + part_[((gl2 * 4 + 1) * 4 + rr) * 32 + bb]
                      + part_[((gl2 * 4 + 2) * 4 + rr) * 32 + bb]
                      + part_[((gl2 * 4 + 3) * 4 + rr) * 32 + bb];
            int row = g2 * 4 + rr;
            if (row < 768) {
              ws[OFF_U + bb * 768 + row] = sum + attn_b[row];
            } else if (row < 3072) {
              int r2 = row - 768;
              ws[OFF_GH + r2 * 32 + bb] = sum + bhh[r2];
            } else if (row < 3840) {
              int r2 = row - 3072;
              ws[OFF_CALL + i * 24576 + bb * 768 + r2] = sum + ws[OFF_CP + r2 * 32 + bb];
            } else {
              int o = row - 3840;
              float val = sum + ws[OFF_FP + o * 32 + bb];
              ws[OFF_HIST + i * 12288 + bb * 384 + o] = val;
              outp[bb * 24576 + o * 64 + (i - 1)] = val;
            }
          }
        }
        __syncthreads();
      }
    }
    gridbar(bar);

    // ================= Phase B1: scores+partial softmax (64 blocks) | gie/fe/ge (192 blocks)
    if (bid < 64) {
      int bb = bid & 31, tc = bid >> 5;
      int tl = tid >> 5, kc = tid & 31;
      int t = tc * 32 + tl;
      float s = 0.f;
      if (t <= i) {
        const float* ub = ws + OFF_U + bb * 768;
        const float* cb = ws + OFF_CALL + t * 24576 + bb * 768;
#pragma unroll 6
        for (int m = 0; m < 24; ++m) {
          int k = kc + 32 * m;
          s = fmaf(fast_tanh(ub[k] + cb[k]), vW[k], s);
        }
      }
      for (int d2 = 16; d2 >= 1; d2 >>= 1) s += __shfl_xor(s, d2);
      if (kc == 0) sred[tl] = s;
      __syncthreads();
      if (tid < 32) {
        int t2 = tc * 32 + tid;
        float p = 0.f;
        if (t2 <= i) { p = __expf(sred[tid] - Mv); ws[OFF_SC + bb * 64 + t2] = p; }
        pv2[tid] = p;
      }
      __syncthreads();
      if (tid == 0) {
        float Dt = 0.f;
        for (int q = 0; q < 32; ++q) Dt += pv2[q];
        ws[OFF_PD + bb * 2 + tc] = Dt;
      }
      float accp = 0.f; int o_ = 0, g_ = 0;
      if (tid < 768) {
        g_ = tid / 384; o_ = tid - g_ * 384;
        for (int q = 0; q < 16; ++q) {
          int tl2 = g_ * 16 + q;
          float p = pv2[tl2];
          int t3 = tc * 32 + tl2;
          if (p > 0.f) accp = fmaf(p, ws[OFF_HIST + t3 * 12288 + bb * 384 + o_], accp);
        }
        if (g_ == 0) pwred_[o_] = accp;
      }
      __syncthreads();
      if (tid >= 384 && tid < 768)
        ws[OFF_PW + (bb * 2 + tc) * 384 + o_] = pwred_[o_] + accp;
    } else {
      // gie_i / fe_i / ge_i : 864 groups of 4 rows, K=384
      int bb2 = bid - 64;
      int gb = (bb2 * 9) >> 1, geE = ((bb2 + 1) * 9) >> 1;
      int gl = wv >> 2, kq = wv & 3;
      int tok = target[b32 * 65 + i];
      const float* xe = emb + tok * 384 + kq * 96 + kh * 48;
      int nsw = (geE - gb + 3) >> 2;
      for (int sw = 0; sw < nsw; ++sw) {
        int g = gb + sw * 4 + gl;
        if (g < geE) {
          const float* Wb; int ld;
          if (g < 576)      { Wb = Wih + (g * 4) * 768;                    ld = 768;  }
          else if (g < 672) { Wb = fcW + ((g - 576) * 4) * 1536 + 1152;    ld = 1536; }
          else              { Wb = ws + OFF_GEM + ((g - 672) * 4) * 384;   ld = 384;  }
          const float* wp = Wb + kq * 96 + kh * 48;
          float a0 = 0.f, a1 = 0.f, a2 = 0.f, a3 = 0.f;
#pragma unroll 6
          for (int q = 0; q < 12; ++q) {
            float4 xv = ((const float4*)xe)[q];
            float4 w0 = ((const float4*)(wp))[q];
            float4 w1 = ((const float4*)(wp + ld))[q];
            float4 w2 = ((const float4*)(wp + 2 * ld))[q];
            float4 w3 = ((const float4*)(wp + 3 * ld))[q];
            a0 = fmaf(w0.x, xv.x, a0); a0 = fmaf(w0.y, xv.y, a0);
            a0 = fmaf(w0.z, xv.z, a0); a0 = fmaf(w0.w, xv.w, a0);
            a1 = fmaf(w1.x, xv.x, a1); a1 = fmaf(w1.y, xv.y, a1);
            a1 = fmaf(w1.z, xv.z, a1); a1 = fmaf(w1.w, xv.w, a1);
            a2 = fmaf(w2.x, xv.x, a2); a2 = fmaf(w2.y, xv.y, a2);
            a2 = fmaf(w2.z, xv.z, a2); a2 = fmaf(w2.w, xv.w, a2);
            a3 = fmaf(w3.x, xv.x, a3); a3 = fmaf(w3.y, xv.y, a3);
            a3 = fmaf(w3.z, xv.z, a3); a3 = fmaf(w3.w, xv.w, a3);
          }
          a0 += __shfl_xor(a0, 32); a1 += __shfl_xor(a1, 32);
          a2 += __shfl_xor(a2, 32); a3 += __shfl_xor(a3, 32);
          if (kh == 0) {
            float* pp = part_ + ((gl * 4 + kq) * 4) * 32 + b32;
            pp[0] = a0; pp[32] = a1; pp[64] = a2; pp[96] = a3;
          }
        }
        __syncthreads();
        if (tid < 512) {
          int gl2 = tid >> 7, rr = (tid >> 5) & 3, bb = tid & 31;
          int g2 = gb + sw * 4 + gl2;
          if (g2 < geE) {
            float sum = part_[((gl2 * 4 + 0) * 4 + rr) * 32 + bb]
                      + part_[((gl2 * 4 + 1) * 4 + rr) * 32 + bb]
                      + part_[((gl2 * 4 + 2) * 4 + rr) * 32 + bb]
                      + part_[((gl2 * 4 + 3) * 4 + rr) * 32 + bb];
            int row = g2 * 4 + rr;
            if (row < 2304) {
              ws[OFF_GIE + row * 32 + bb] = sum + bih[row];
            } else if (row < 2688) {
              int o2 = row - 2304;
              ws[OFF_FE + o2 * 32 + bb] = sum + fcb[o2];
            } else {
              int r2 = row - 2688;
              ws[OFF_GE + r2 * 32 + bb] = sum + ws[OFF_GB + r2];
            }
          }
        }
        __syncthreads();
      }
    }
    gridbar(bar);

    // ================= Phase C: w assembly, attn out, giw, fpart/cpart, gates ====
    {
      if (tid < 32) {
        float D = ws[OFF_PD + tid * 2] + ws[OFF_PD + tid * 2 + 1];
        D_lds[tid] = __fdividef(1.0f, D);
      }
      __syncthreads();
      for (int e = tid; e < 12288; e += 1024) {
        int bb = e / 384, o = e - bb * 384;
        float acc = ws[OFF_PW + (bb * 2) * 384 + o] + ws[OFF_PW + (bb * 2 + 1) * 384 + o];
        w_lds[bb * 388 + o] = acc * D_lds[bb];
      }
      __syncthreads();
      // attention outputs
      if (bid < 64 && tid < 32) {
        int bb = bid >> 1, th = bid & 1;
        int t = th * 32 + tid;
        if (t <= i)
          outp[ATTN_OFF + bb * 2080 + (i * (i + 1)) / 2 + t] =
              ws[OFF_SC + bb * 64 + t] * D_lds[bb];
      }
      // giw: 9 local rows (K=384, x = w in LDS)
      if (wv < 9) {
        int jl = wv / 3, gg = wv % 3;
        int grow = bid * 3 + jl + gg * 768;
        const float* wp = Wih + grow * 768 + 384 + kh * 192;
        const float* xp = &w_lds[b32 * 388] + kh * 192;
        float acc = 0.f;
#pragma unroll 8
        for (int q = 0; q < 48; ++q) {
          float4 wq4 = ((const float4*)wp)[q];
          float4 xq4 = ((const float4*)xp)[q];
          acc = fmaf(wq4.x, xq4.x, acc); acc = fmaf(wq4.y, xq4.y, acc);
          acc = fmaf(wq4.z, xq4.z, acc); acc = fmaf(wq4.w, xq4.w, acc);
        }
        acc += __shfl_xor(acc, 32);
        if (kh == 0) giw_lds[(jl * 3 + gg) * 32 + b32] = acc;
      }
      // fpart/cpart: 1152 flat rows (K=384, x = w in LDS), one row per wave slot
      {
        int rb = (wg * 1152) >> 12, re = ((wg + 1) * 1152) >> 12;
        for (int r = rb; r < re; ++r) {
          const float* wp; float addv; float* dst;
          if (r < 384) {
            wp = fcW + r * 1536 + 768;
            addv = ws[OFF_FE + r * 32 + b32];
            dst = ws + OFF_FP + r * 32 + b32;
          } else {
            int r2 = r - 384;
            wp = ws + OFF_GWM + r2 * 384;
            addv = ws[OFF_GE + r2 * 32 + b32];
            dst = ws + OFF_CP + r2 * 32 + b32;
          }
          const float* wpp = wp + kh * 192;
          const float* xp = &w_lds[b32 * 388] + kh * 192;
          float acc = 0.f;
#pragma unroll 8
          for (int q = 0; q < 48; ++q) {
            float4 wq4 = ((const float4*)wpp)[q];
            float4 xq4 = ((const float4*)xp)[q];
            acc = fmaf(wq4.x, xq4.x, acc); acc = fmaf(wq4.y, xq4.y, acc);
            acc = fmaf(wq4.z, xq4.z, acc); acc = fmaf(wq4.w, xq4.w, acc);
          }
          acc += __shfl_xor(acc, 32);
          if (kh == 0) *dst = acc + addv;
        }
      }
      __syncthreads();
      // gates: this block's 3 j's
      if (tid < 96) {
        int jl = tid >> 5, bb = tid & 31;
        int j = bid * 3 + jl;
        const float* gie = ws + OFF_GIE;
        const float* gh = ws + OFF_GH;
        float gr = gie[j * 32 + bb] + giw_lds[(jl * 3 + 0) * 32 + bb] + gh[j * 32 + bb];
        float gz = gie[(j + 768) * 32 + bb] + giw_lds[(jl * 3 + 1) * 32 + bb] + gh[(j + 768) * 32 + bb];
        float gn = gie[(j + 1536) * 32 + bb] + giw_lds[(jl * 3 + 2) * 32 + bb];
        float ghn = gh[(j + 1536) * 32 + bb];
        float r_ = sigmoidf_(gr);
        float z_ = sigmoidf_(gz);
        float n_ = fast_tanh(fmaf(r_, ghn, gn));
        float hold = ws[OFF_H + (i & 1) * 24576 + bb * 768 + j];
        ws[OFF_H + ((i + 1) & 1) * 24576 + bb * 768 + j] = (1.0f - z_) * n_ + z_ * hold;
      }
    }
    gridbar(bar);
  }

  // ============ epilogue: out_63 = F_h h_64 + fpart_63 ============
  if (wg < 384) {
    int o = wg;
    const float* hp = ws + OFF_H + 0 * 24576 + b32 * 768 + kh * 384;
    const float* wp = fcW + o * 1536 + kh * 384;
    float acc = 0.f;
#pragma unroll 8
    for (int q = 0; q < 96; ++q) {
      float4 wq4 = ((const float4*)wp)[q];
      float4 xq4 = ((const float4*)hp)[q];
      acc = fmaf(wq4.x, xq4.x, acc); acc = fmaf(wq4.y, xq4.y, acc);
      acc = fmaf(wq4.z, xq4.z, acc); acc = fmaf(wq4.w, xq4.w, acc);
    }
    acc += __shfl_xor(acc, 32);
    if (kh == 0) outp[b32 * 24576 + o * 64 + 63] = acc + ws[OFF_FP + o * 32 + b32];
  }
}

extern "C" void kernel_launch(void* const* d_in, const int* in_sizes, int n_in,
                              void* d_out, int out_size, void* d_ws, size_t ws_size,
                              hipStream_t stream) {
  const int*   target = (const int*)d_in[0];
  const float* hidden = (const float*)d_in[1];
  // d_in[2] = teacher_forcing_ratio (== 1, deterministic path)
  const float* emb    = (const float*)d_in[3];
  const float* attn_W = (const float*)d_in[4];
  const float* attn_b = (const float*)d_in[5];
  const float* vW     = (const float*)d_in[6];
  const float* Wih    = (const float*)d_in[7];
  const float* Whh    = (const float*)d_in[8];
  const float* bih    = (const float*)d_in[9];
  const float* bhh    = (const float*)d_in[10];
  const float* fcW    = (const float*)d_in[11];
  const float* fcb    = (const float*)d_in[12];
  float* outp = (float*)d_out;
  float* ws   = (float*)d_ws;

  kprepG<<<289, 256, 0, stream>>>(attn_W, fcW, fcb, ws);
  kprep0<<<256, 256, 0, stream>>>(hidden, vW, ws);

  void* args[] = {(void*)&target, (void*)&emb, (void*)&attn_W, (void*)&attn_b,
                  (void*)&vW, (void*)&Wih, (void*)&Whh, (void*)&bih, (void*)&bhh,
                  (void*)&fcW, (void*)&fcb, (void*)&outp, (void*)&ws};
  hipLaunchCooperativeKernel((const void*)kmain, dim3(256), dim3(1024), args, 0, stream);
}

// Round 2
// 5583.227 us; speedup vs baseline: 2.5110x; 2.5110x over previous
//
#include <hip/hip_runtime.h>

// GRU decoder with Bahdanau attention, B=32, T=64, O=E=384, H=768.
// Persistent cooperative kernel, 3 grid barriers per step.
// Coherence scheme: NO cache-invalidating fences. Cross-block mutable data
// uses sc0/sc1 (LLC-coherent, L1/L2-bypassing) loads/stores via inline asm;
// write-once data (c_all, HIST) uses sc1 write-through stores + cached reads;
// weights stay L2-cached across all steps.

#define DEVI static __device__ __forceinline__
typedef float f32x4 __attribute__((ext_vector_type(4)));

constexpr int ATTN_OFF = 786432;

// ws offsets (floats)
constexpr int OFF_H    = 0;        // 2 x (32*768) h double buffer (b,k)
constexpr int OFF_U    = 49152;    // (b,k) 32*768
constexpr int OFF_GH   = 73728;    // (row,b) 2304*32
constexpr int OFF_GIE  = 147456;   // (row,b) 2304*32
constexpr int OFF_FE   = 221184;   // (row,b) 384*32
constexpr int OFF_GE   = 233472;   // (row,b) 768*32
constexpr int OFF_FP   = 258048;   // (row,b) 384*32
constexpr int OFF_CP   = 270336;   // (row,b) 768*32
constexpr int OFF_SC   = 294912;   // (b,t) 32*64  p=exp(s-M)
constexpr int OFF_PD   = 296960;   // (b,tc) 32*2
constexpr int OFF_PW   = 297024;   // (b*2+tc, o) 64*384
constexpr int OFF_CALL = 321600;   // c_all (t,b,k) 64*32*768   write-once
constexpr int OFF_HIST = 1894464;  // hist (t,b,o) 64*32*384    write-once
constexpr int OFF_GHM  = 2680896;  // Gh (768,768) = A_o F_h    read-only
constexpr int OFF_GWM  = 3270720;  // Gw (768,384) = A_o F_w    read-only
constexpr int OFF_GEM  = 3565632;  // Ge (768,384) = A_o F_e    read-only
constexpr int OFF_GB   = 3860544;  // 768 = A_o fc_b            read-only
constexpr int OFF_V1   = 3861312;  // M = sum|v|                read-only
constexpr int OFF_BAR  = 3861344;  // barrier, 1152 u32

DEVI float fast_tanh(float x) {
  float a = __builtin_fabsf(x);
  float e = __expf(-2.0f * a);
  float r = __fdividef(1.0f - e, 1.0f + e);
  return __builtin_copysignf(r, x);
}
DEVI float sigmoidf_(float x) {
  return __fdividef(1.0f, 1.0f + __expf(-x));
}

// ---- uncached (LLC-coherent) access helpers: sc0 sc1, one waitcnt per block ----
DEVI float nc_ld_f1(const float* p) {
  float r;
  asm volatile("global_load_dword %0, %1, off sc0 sc1\n\ts_waitcnt vmcnt(0)"
               : "=&v"(r) : "v"(p) : "memory");
  return r;
}
DEVI void nc_ld_f1x2(const float* p0, const float* p1, float& r0, float& r1) {
  asm volatile(
      "global_load_dword %0, %2, off sc0 sc1\n\t"
      "global_load_dword %1, %3, off sc0 sc1\n\t"
      "s_waitcnt vmcnt(0)"
      : "=&v"(r0), "=&v"(r1) : "v"(p0), "v"(p1) : "memory");
}
DEVI void nc_ld_f1x6(const float* p0, const float* p1, const float* p2,
                     const float* p3, const float* p4, const float* p5,
                     float& r0, float& r1, float& r2, float& r3, float& r4, float& r5) {
  asm volatile(
      "global_load_dword %0, %6, off sc0 sc1\n\t"
      "global_load_dword %1, %7, off sc0 sc1\n\t"
      "global_load_dword %2, %8, off sc0 sc1\n\t"
      "global_load_dword %3, %9, off sc0 sc1\n\t"
      "global_load_dword %4, %10, off sc0 sc1\n\t"
      "global_load_dword %5, %11, off sc0 sc1\n\t"
      "s_waitcnt vmcnt(0)"
      : "=&v"(r0), "=&v"(r1), "=&v"(r2), "=&v"(r3), "=&v"(r4), "=&v"(r5)
      : "v"(p0), "v"(p1), "v"(p2), "v"(p3), "v"(p4), "v"(p5) : "memory");
}
DEVI void nc_ld_f4x6(const float* p, f32x4& r0, f32x4& r1, f32x4& r2,
                     f32x4& r3, f32x4& r4, f32x4& r5) {
  asm volatile(
      "global_load_dwordx4 %0, %6, off sc0 sc1\n\t"
      "global_load_dwordx4 %1, %6, off offset:16 sc0 sc1\n\t"
      "global_load_dwordx4 %2, %6, off offset:32 sc0 sc1\n\t"
      "global_load_dwordx4 %3, %6, off offset:48 sc0 sc1\n\t"
      "global_load_dwordx4 %4, %6, off offset:64 sc0 sc1\n\t"
      "global_load_dwordx4 %5, %6, off offset:80 sc0 sc1\n\t"
      "s_waitcnt vmcnt(0)"
      : "=&v"(r0), "=&v"(r1), "=&v"(r2), "=&v"(r3), "=&v"(r4), "=&v"(r5)
      : "v"(p) : "memory");
}
DEVI void nc_ld_f4x3x2(const float* pa, const float* pb, f32x4& r0, f32x4& r1,
                       f32x4& r2, f32x4& r3, f32x4& r4, f32x4& r5) {
  asm volatile(
      "global_load_dwordx4 %0, %6, off sc0 sc1\n\t"
      "global_load_dwordx4 %1, %6, off offset:16 sc0 sc1\n\t"
      "global_load_dwordx4 %2, %6, off offset:32 sc0 sc1\n\t"
      "global_load_dwordx4 %3, %7, off sc0 sc1\n\t"
      "global_load_dwordx4 %4, %7, off offset:16 sc0 sc1\n\t"
      "global_load_dwordx4 %5, %7, off offset:32 sc0 sc1\n\t"
      "s_waitcnt vmcnt(0)"
      : "=&v"(r0), "=&v"(r1), "=&v"(r2), "=&v"(r3), "=&v"(r4), "=&v"(r5)
      : "v"(pa), "v"(pb) : "memory");
}
DEVI void nc_st_f1(float* p, float v_) {
  asm volatile("global_store_dword %0, %1, off sc0 sc1" :: "v"(p), "v"(v_) : "memory");
}

// ---- relaxed-only grid barrier (no cache maintenance) ----
DEVI void gridbar(unsigned* bar) {
  asm volatile("s_waitcnt vmcnt(0)" ::: "memory");  // all sc1 stores at LLC
  __syncthreads();
  if (threadIdx.x == 0) {
    unsigned* super = bar + 1024;
    unsigned* gen   = bar + 1056;
    unsigned g = __hip_atomic_load(gen, __ATOMIC_RELAXED, __HIP_MEMORY_SCOPE_AGENT);
    int grp = (int)(blockIdx.x >> 3);
    unsigned a = __hip_atomic_fetch_add(bar + grp * 32, 1u, __ATOMIC_RELAXED, __HIP_MEMORY_SCOPE_AGENT);
    bool released = false;
    if (a == 7u) {
      __hip_atomic_store(bar + grp * 32, 0u, __ATOMIC_RELAXED, __HIP_MEMORY_SCOPE_AGENT);
      unsigned s = __hip_atomic_fetch_add(super, 1u, __ATOMIC_RELAXED, __HIP_MEMORY_SCOPE_AGENT);
      if (s == 31u) {
        __hip_atomic_store(super, 0u, __ATOMIC_RELAXED, __HIP_MEMORY_SCOPE_AGENT);
        __hip_atomic_fetch_add(gen, 1u, __ATOMIC_RELAXED, __HIP_MEMORY_SCOPE_AGENT);
        released = true;
      }
    }
    if (!released) {
      while (__hip_atomic_load(gen, __ATOMIC_RELAXED, __HIP_MEMORY_SCOPE_AGENT) == g) {
        __builtin_amdgcn_s_sleep(1);
      }
    }
  }
  __syncthreads();
}

// ---------- precompute kernel: Gh/Gw/Ge/gb ----------
__global__ __launch_bounds__(256) void kprepG(const float* __restrict__ attn_W,
                                              const float* __restrict__ fcW,
                                              const float* __restrict__ fcb,
                                              float* __restrict__ ws) {
  int bid = blockIdx.x, tid = threadIdx.x;
  if (bid < 288) {
    int rt = bid / 6, kt = bid % 6;
    int r0 = rt * 16;
    int kg = kt * 256 + tid;
    float acc[16];
#pragma unroll
    for (int q = 0; q < 16; ++q) acc[q] = 0.f;
    for (int o = 0; o < 384; ++o) {
      float f = fcW[o * 1536 + kg];
#pragma unroll
      for (int q = 0; q < 16; ++q)
        acc[q] = fmaf(attn_W[(r0 + q) * 1152 + 768 + o], f, acc[q]);
    }
#pragma unroll
    for (int q = 0; q < 16; ++q) {
      int r = r0 + q;
      if (kg < 768)       ws[OFF_GHM + r * 768 + kg] = acc[q];
      else if (kg < 1152) ws[OFF_GWM + r * 384 + (kg - 768)] = acc[q];
      else                ws[OFF_GEM + r * 384 + (kg - 1152)] = acc[q];
    }
  } else {
    for (int r = tid; r < 768; r += 256) {
      float a = 0.f;
      for (int o = 0; o < 384; ++o) a = fmaf(attn_W[r * 1152 + 768 + o], fcb[o], a);
      ws[OFF_GB + r] = a;
    }
  }
}

// ---------- prep kernel: zeros, h copy, M, barrier ----------
__global__ __launch_bounds__(256) void kprep0(const float* __restrict__ hidden,
                                              const float* __restrict__ vW,
                                              float* __restrict__ ws) {
  int bid = blockIdx.x, tid = threadIdx.x;
  int gtid = bid * 256 + tid;
  if (gtid < 24576) {
    ws[OFF_CALL + gtid] = 0.f;
    ws[OFF_H + gtid] = hidden[gtid];
  } else if (gtid < 36864) {
    ws[OFF_HIST + (gtid - 24576)] = 0.f;
  }
  if (gtid < 1152) ((unsigned*)(ws + OFF_BAR))[gtid] = 0u;
  if (bid == 0) {
    __shared__ float vred[256];
    float a = 0.f;
    for (int k = tid; k < 768; k += 256) a += __builtin_fabsf(vW[k]);
    vred[tid] = a;
    __syncthreads();
    for (int s2 = 128; s2 > 0; s2 >>= 1) {
      if (tid < s2) vred[tid] += vred[tid + s2];
      __syncthreads();
    }
    if (tid == 0) ws[OFF_V1] = vred[0];
  }
}

// ---------- main persistent cooperative kernel ----------
__global__ void __launch_bounds__(1024)
kmain(const int* __restrict__ target, const float* __restrict__ emb,
      const float* __restrict__ attn_W, const float* __restrict__ attn_b,
      const float* __restrict__ vW,
      const float* __restrict__ Wih, const float* __restrict__ Whh,
      const float* __restrict__ bih, const float* __restrict__ bhh,
      const float* __restrict__ fcW, const float* __restrict__ fcb,
      float* __restrict__ outp, float* __restrict__ ws) {
  const int bid = blockIdx.x, tid = threadIdx.x;
  const int wv = tid >> 6, lane = tid & 63;
  const int b32 = lane & 31, kh = lane >> 5;
  const int wg = bid * 16 + wv;
  unsigned* bar = (unsigned*)(ws + OFF_BAR);

  // aliased LDS: phase A/B use part_ (and B-left sred/pv2/pwred_),
  // phase C uses w_lds/giw/D. 12736 floats = 50944 B.
  __shared__ __align__(16) float smem[12736];
  float* part_  = smem;           // 4096 (phase A), 2048 (phase B-right)
  float* w_lds  = smem;           // 12416 = 32*388 (phase C)
  float* giw_lds = smem + 12416;  // 288 (phase C)
  float* D_lds  = smem + 12704;   // 32 (phase C)
  float* sred   = smem;           // 32 (phase B-left)
  float* pv2    = smem + 32;      // 32 (phase B-left)
  float* pwred_ = smem + 64;      // 384 (phase B-left)

  const float Mv = ws[OFF_V1];

  for (int i = 0; i < 64; ++i) {
    // ---- load this thread's h-slice once (uncached), k = wv*48 + kh*24 + [0,24) ----
    f32x4 xv[6];
    {
      const float* xp = ws + OFF_H + (i & 1) * 24576 + b32 * 768 + wv * 48 + kh * 24;
      nc_ld_f4x6(xp, xv[0], xv[1], xv[2], xv[3], xv[4], xv[5]);
    }

    // ================= Phase A: u, gh, c_i, out_{i-1} (4224 rows = 1056 groups, K=768)
    {
      int gb = (bid * 1056) >> 8;
      int geE = ((bid + 1) * 1056) >> 8;
      int nsw = (geE - gb + 1) >> 1;
      for (int sw = 0; sw < nsw; ++sw) {
        int g0 = gb + sw * 2;
        float a[8];
#pragma unroll
        for (int q = 0; q < 8; ++q) a[q] = 0.f;
#pragma unroll
        for (int gg = 0; gg < 2; ++gg) {
          int g = g0 + gg;
          if (g < geE && !(i == 0 && g >= 768)) {
            const float* Wb; int ld;
            if (g < 192)      { Wb = attn_W + (g * 4) * 1152;               ld = 1152; }
            else if (g < 768) { Wb = Whh + ((g - 192) * 4) * 768;           ld = 768;  }
            else if (g < 960) { Wb = ws + OFF_GHM + ((g - 768) * 4) * 768;  ld = 768;  }
            else              { Wb = fcW + ((g - 960) * 4) * 1536;          ld = 1536; }
            const float* wp = Wb + wv * 48 + kh * 24;
#pragma unroll
            for (int q = 0; q < 6; ++q) {
              f32x4 xq = xv[q];
#pragma unroll
              for (int r = 0; r < 4; ++r) {
                f32x4 wq = *(const f32x4*)(wp + r * ld + q * 4);
                float t0 = fmaf(wq[0], xq[0], a[gg * 4 + r]);
                t0 = fmaf(wq[1], xq[1], t0);
                t0 = fmaf(wq[2], xq[2], t0);
                a[gg * 4 + r] = fmaf(wq[3], xq[3], t0);
              }
            }
          }
        }
#pragma unroll
        for (int r8 = 0; r8 < 8; ++r8) a[r8] += __shfl_xor(a[r8], 32);
        if (kh == 0) {
#pragma unroll
          for (int r8 = 0; r8 < 8; ++r8) part_[wv * 256 + r8 * 32 + b32] = a[r8];
        }
        __syncthreads();
        if (tid < 256) {
          int rr = tid >> 5, bb = tid & 31;
          int g2 = g0 + (rr >> 2);
          if (g2 < geE && !(i == 0 && g2 >= 768)) {
            float sum = 0.f;
#pragma unroll
            for (int wvv = 0; wvv < 16; ++wvv) sum += part_[wvv * 256 + tid];
            int row = g0 * 4 + rr;
            if (row < 768) {
              nc_st_f1(ws + OFF_U + bb * 768 + row, sum + attn_b[row]);
            } else if (row < 3072) {
              int r2 = row - 768;
              nc_st_f1(ws + OFF_GH + r2 * 32 + bb, sum + bhh[r2]);
            } else if (row < 3840) {
              int r2 = row - 3072;
              float cp = nc_ld_f1(ws + OFF_CP + r2 * 32 + bb);
              nc_st_f1(ws + OFF_CALL + i * 24576 + bb * 768 + r2, sum + cp);
            } else {
              int o = row - 3840;
              float fp = nc_ld_f1(ws + OFF_FP + o * 32 + bb);
              float val = sum + fp;
              nc_st_f1(ws + OFF_HIST + i * 12288 + bb * 384 + o, val);
              outp[bb * 24576 + o * 64 + (i - 1)] = val;  // cached, host-read only
            }
          }
        }
        __syncthreads();
      }
    }
    gridbar(bar);

    // ================= Phase B1: scores+partial softmax (64 blocks) | gie/fe/ge (192)
    if (bid < 64) {
      int bb = bid & 31, tc = bid >> 5;
      int tl = tid >> 5, kc = tid & 31;
      int t = tc * 32 + tl;
      float s = 0.f;
      if (t <= i) {
        const float* ub = ws + OFF_U + bb * 768 + kc * 24;
        const float* cb = ws + OFF_CALL + t * 24576 + bb * 768 + kc * 24;  // cached, write-once
        const float* vp = vW + kc * 24;
        f32x4 u_[6];
        nc_ld_f4x6(ub, u_[0], u_[1], u_[2], u_[3], u_[4], u_[5]);
#pragma unroll
        for (int q = 0; q < 6; ++q) {
          f32x4 cq = *(const f32x4*)(cb + q * 4);
          f32x4 vq = *(const f32x4*)(vp + q * 4);
#pragma unroll
          for (int e = 0; e < 4; ++e)
            s = fmaf(fast_tanh(u_[q][e] + cq[e]), vq[e], s);
        }
      }
      for (int d2 = 16; d2 >= 1; d2 >>= 1) s += __shfl_xor(s, d2);
      if (kc == 0) sred[tl] = s;
      __syncthreads();
      if (tid < 32) {
        int t2 = tc * 32 + tid;
        float p = 0.f;
        if (t2 <= i) { p = __expf(sred[tid] - Mv); nc_st_f1(ws + OFF_SC + bb * 64 + t2, p); }
        pv2[tid] = p;
      }
      __syncthreads();
      if (tid == 0) {
        float Dt = 0.f;
        for (int q = 0; q < 32; ++q) Dt += pv2[q];
        nc_st_f1(ws + OFF_PD + bb * 2 + tc, Dt);
      }
      float accp = 0.f; int o_ = 0, g_ = 0;
      if (tid < 768) {
        g_ = tid / 384; o_ = tid - g_ * 384;
        int base_t = tc * 32 + g_ * 16;
        int nq = i - base_t + 1;
        nq = nq < 0 ? 0 : (nq > 16 ? 16 : nq);
        for (int q = 0; q < nq; ++q) {
          float p = pv2[g_ * 16 + q];
          accp = fmaf(p, ws[OFF_HIST + (base_t + q) * 12288 + bb * 384 + o_], accp);  // cached
        }
        if (g_ == 0) pwred_[o_] = accp;
      }
      __syncthreads();
      if (tid >= 384 && tid < 768)
        nc_st_f1(ws + OFF_PW + (bb * 2 + tc) * 384 + o_, pwred_[o_] + accp);
    } else {
      // gie_i / fe_i / ge_i : 864 groups of 4 rows, K=384 (x = emb, cached)
      int bb2 = bid - 64;
      int gb = (bb2 * 9) >> 1, geE = ((bb2 + 1) * 9) >> 1;
      int gl = wv >> 2, kq = wv & 3;
      int tok = target[b32 * 65 + i];
      const float* xe = emb + tok * 384 + kq * 96 + kh * 48;
      int nsw = (geE - gb + 3) >> 2;
      for (int sw = 0; sw < nsw; ++sw) {
        int g = gb + sw * 4 + gl;
        if (g < geE) {
          const float* Wb; int ld;
          if (g < 576)      { Wb = Wih + (g * 4) * 768;                    ld = 768;  }
          else if (g < 672) { Wb = fcW + ((g - 576) * 4) * 1536 + 1152;    ld = 1536; }
          else              { Wb = ws + OFF_GEM + ((g - 672) * 4) * 384;   ld = 384;  }
          const float* wp = Wb + kq * 96 + kh * 48;
          float a0 = 0.f, a1 = 0.f, a2 = 0.f, a3 = 0.f;
#pragma unroll 6
          for (int q = 0; q < 12; ++q) {
            f32x4 xq = *(const f32x4*)(xe + q * 4);
            f32x4 w0 = *(const f32x4*)(wp + q * 4);
            f32x4 w1 = *(const f32x4*)(wp + ld + q * 4);
            f32x4 w2 = *(const f32x4*)(wp + 2 * ld + q * 4);
            f32x4 w3 = *(const f32x4*)(wp + 3 * ld + q * 4);
            a0 = fmaf(w0[0], xq[0], a0); a0 = fmaf(w0[1], xq[1], a0);
            a0 = fmaf(w0[2], xq[2], a0); a0 = fmaf(w0[3], xq[3], a0);
            a1 = fmaf(w1[0], xq[0], a1); a1 = fmaf(w1[1], xq[1], a1);
            a1 = fmaf(w1[2], xq[2], a1); a1 = fmaf(w1[3], xq[3], a1);
            a2 = fmaf(w2[0], xq[0], a2); a2 = fmaf(w2[1], xq[1], a2);
            a2 = fmaf(w2[2], xq[2], a2); a2 = fmaf(w2[3], xq[3], a2);
            a3 = fmaf(w3[0], xq[0], a3); a3 = fmaf(w3[1], xq[1], a3);
            a3 = fmaf(w3[2], xq[2], a3); a3 = fmaf(w3[3], xq[3], a3);
          }
          a0 += __shfl_xor(a0, 32); a1 += __shfl_xor(a1, 32);
          a2 += __shfl_xor(a2, 32); a3 += __shfl_xor(a3, 32);
          if (kh == 0) {
            float* pp = part_ + ((gl * 4 + kq) * 4) * 32 + b32;
            pp[0] = a0; pp[32] = a1; pp[64] = a2; pp[96] = a3;
          }
        }
        __syncthreads();
        if (tid < 512) {
          int gl2 = tid >> 7, rr = (tid >> 5) & 3, bb = tid & 31;
          int g2 = gb + sw * 4 + gl2;
          if (g2 < geE) {
            float sum = part_[((gl2 * 4 + 0) * 4 + rr) * 32 + bb]
                      + part_[((gl2 * 4 + 1) * 4 + rr) * 32 + bb]
                      + part_[((gl2 * 4 + 2) * 4 + rr) * 32 + bb]
                      + part_[((gl2 * 4 + 3) * 4 + rr) * 32 + bb];
            int row = g2 * 4 + rr;
            if (row < 2304) {
              nc_st_f1(ws + OFF_GIE + row * 32 + bb, sum + bih[row]);
            } else if (row < 2688) {
              int o2 = row - 2304;
              nc_st_f1(ws + OFF_FE + o2 * 32 + bb, sum + fcb[o2]);
            } else {
              int r2 = row - 2688;
              nc_st_f1(ws + OFF_GE + r2 * 32 + bb, sum + ws[OFF_GB + r2]);
            }
          }
        }
        __syncthreads();
      }
    }
    gridbar(bar);

    // ================= Phase C: w assembly, attn out, giw, fpart/cpart, gates ====
    {
      if (tid < 32) {
        float d0, d1;
        nc_ld_f1x2(ws + OFF_PD + tid * 2, ws + OFF_PD + tid * 2 + 1, d0, d1);
        D_lds[tid] = __fdividef(1.0f, d0 + d1);
      }
      __syncthreads();
      {
        int bb = tid >> 5, o = (tid & 31) * 12;
        const float* pa = ws + OFF_PW + (bb * 2) * 384 + o;
        const float* pb = pa + 384;
        f32x4 r0, r1, r2, r3, r4, r5;
        nc_ld_f4x3x2(pa, pb, r0, r1, r2, r3, r4, r5);
        float dinv = D_lds[bb];
        f32x4 w0 = (r0 + r3) * dinv;
        f32x4 w1 = (r1 + r4) * dinv;
        f32x4 w2 = (r2 + r5) * dinv;
        *(f32x4*)&w_lds[bb * 388 + o]     = w0;
        *(f32x4*)&w_lds[bb * 388 + o + 4] = w1;
        *(f32x4*)&w_lds[bb * 388 + o + 8] = w2;
      }
      __syncthreads();
      // attention outputs
      if (bid < 64 && tid < 32) {
        int bb = bid >> 1, th = bid & 1;
        int t = th * 32 + tid;
        if (t <= i) {
          float sc = nc_ld_f1(ws + OFF_SC + bb * 64 + t);
          outp[ATTN_OFF + bb * 2080 + (i * (i + 1)) / 2 + t] = sc * D_lds[bb];
        }
      }
      // giw: 9 local rows (K=384, x = w in LDS)
      if (wv < 9) {
        int jl = wv / 3, gg = wv % 3;
        int grow = bid * 3 + jl + gg * 768;
        const float* wp = Wih + grow * 768 + 384 + kh * 192;
        const float* xp = &w_lds[b32 * 388] + kh * 192;
        float acc = 0.f;
#pragma unroll 8
        for (int q = 0; q < 48; ++q) {
          f32x4 wq4 = *(const f32x4*)(wp + q * 4);
          f32x4 xq4 = *(const f32x4*)(xp + q * 4);
          acc = fmaf(wq4[0], xq4[0], acc); acc = fmaf(wq4[1], xq4[1], acc);
          acc = fmaf(wq4[2], xq4[2], acc); acc = fmaf(wq4[3], xq4[3], acc);
        }
        acc += __shfl_xor(acc, 32);
        if (kh == 0) giw_lds[(jl * 3 + gg) * 32 + b32] = acc;
      }
      // fpart/cpart: 1152 flat rows (K=384, x = w in LDS)
      {
        int rb = (wg * 1152) >> 12, re = ((wg + 1) * 1152) >> 12;
        for (int r = rb; r < re; ++r) {
          const float* wp; const float* addp; float* dst;
          if (r < 384) {
            wp = fcW + r * 1536 + 768;
            addp = ws + OFF_FE + r * 32 + b32;
            dst = ws + OFF_FP + r * 32 + b32;
          } else {
            int r2 = r - 384;
            wp = ws + OFF_GWM + r2 * 384;
            addp = ws + OFF_GE + r2 * 32 + b32;
            dst = ws + OFF_CP + r2 * 32 + b32;
          }
          const float* wpp = wp + kh * 192;
          const float* xp = &w_lds[b32 * 388] + kh * 192;
          float acc = 0.f;
#pragma unroll 8
          for (int q = 0; q < 48; ++q) {
            f32x4 wq4 = *(const f32x4*)(wpp + q * 4);
            f32x4 xq4 = *(const f32x4*)(xp + q * 4);
            acc = fmaf(wq4[0], xq4[0], acc); acc = fmaf(wq4[1], xq4[1], acc);
            acc = fmaf(wq4[2], xq4[2], acc); acc = fmaf(wq4[3], xq4[3], acc);
          }
          acc += __shfl_xor(acc, 32);
          if (kh == 0) {
            float addv = nc_ld_f1(addp);
            nc_st_f1(dst, acc + addv);
          }
        }
      }
      __syncthreads();
      // gates
      if (tid < 96) {
        int jl = tid >> 5, bb = tid & 31;
        int j = bid * 3 + jl;
        const float* gie = ws + OFF_GIE;
        const float* gh = ws + OFF_GH;
        float g0, g1, g2, h0, h1, h2;
        nc_ld_f1x6(gie + j * 32 + bb, gie + (j + 768) * 32 + bb, gie + (j + 1536) * 32 + bb,
                   gh + j * 32 + bb, gh + (j + 768) * 32 + bb, gh + (j + 1536) * 32 + bb,
                   g0, g1, g2, h0, h1, h2);
        float hold = nc_ld_f1(ws + OFF_H + (i & 1) * 24576 + bb * 768 + j);
        float gr = g0 + giw_lds[(jl * 3 + 0) * 32 + bb] + h0;
        float gz = g1 + giw_lds[(jl * 3 + 1) * 32 + bb] + h1;
        float gn = g2 + giw_lds[(jl * 3 + 2) * 32 + bb];
        float r_ = sigmoidf_(gr);
        float z_ = sigmoidf_(gz);
        float n_ = fast_tanh(fmaf(r_, h2, gn));
        nc_st_f1(ws + OFF_H + ((i + 1) & 1) * 24576 + bb * 768 + j,
                 (1.0f - z_) * n_ + z_ * hold);
      }
    }
    gridbar(bar);
  }

  // ============ epilogue: out_63 = F_h h_64 + fpart_63 ============
  if (wg < 384) {
    int o = wg;
    const float* hp = ws + OFF_H + 0 * 24576 + b32 * 768 + kh * 384;
    const float* wp = fcW + o * 1536 + kh * 384;
    float acc = 0.f;
    for (int qb = 0; qb < 16; ++qb) {
      f32x4 hh[6];
      nc_ld_f4x6(hp + qb * 24, hh[0], hh[1], hh[2], hh[3], hh[4], hh[5]);
#pragma unroll
      for (int q = 0; q < 6; ++q) {
        f32x4 wq = *(const f32x4*)(wp + qb * 24 + q * 4);
        acc = fmaf(wq[0], hh[q][0], acc); acc = fmaf(wq[1], hh[q][1], acc);
        acc = fmaf(wq[2], hh[q][2], acc); acc = fmaf(wq[3], hh[q][3], acc);
      }
    }
    acc += __shfl_xor(acc, 32);
    if (kh == 0) {
      float fp = nc_ld_f1(ws + OFF_FP + o * 32 + b32);
      outp[b32 * 24576 + o * 64 + 63] = acc + fp;
    }
  }
}

extern "C" void kernel_launch(void* const* d_in, const int* in_sizes, int n_in,
                              void* d_out, int out_size, void* d_ws, size_t ws_size,
                              hipStream_t stream) {
  const int*   target = (const int*)d_in[0];
  const float* hidden = (const float*)d_in[1];
  // d_in[2] = teacher_forcing_ratio (== 1, deterministic path)
  const float* emb    = (const float*)d_in[3];
  const float* attn_W = (const float*)d_in[4];
  const float* attn_b = (const float*)d_in[5];
  const float* vW     = (const float*)d_in[6];
  const float* Wih    = (const float*)d_in[7];
  const float* Whh    = (const float*)d_in[8];
  const float* bih    = (const float*)d_in[9];
  const float* bhh    = (const float*)d_in[10];
  const float* fcW    = (const float*)d_in[11];
  const float* fcb    = (const float*)d_in[12];
  float* outp = (float*)d_out;
  float* ws   = (float*)d_ws;

  kprepG<<<289, 256, 0, stream>>>(attn_W, fcW, fcb, ws);
  kprep0<<<256, 256, 0, stream>>>(hidden, vW, ws);

  void* args[] = {(void*)&target, (void*)&emb, (void*)&attn_W, (void*)&attn_b,
                  (void*)&vW, (void*)&Wih, (void*)&Whh, (void*)&bih, (void*)&bhh,
                  (void*)&fcW, (void*)&fcb, (void*)&outp, (void*)&ws};
  hipLaunchCooperativeKernel((const void*)kmain, dim3(256), dim3(1024), args, 0, stream);
}

// Round 3
// 3620.818 us; speedup vs baseline: 3.8719x; 1.5420x over previous
//
#include <hip/hip_runtime.h>

// GRU decoder with Bahdanau attention, B=32, T=64, O=E=384, H=768.
// Persistent cooperative kernel, 3 grid barriers per step.
// Traffic plan: weights L2-resident per XCD (XCD-major work partition);
// step-rotated write-once arrays (HALL/CALL/HIST/WALL) -> cached coalesced
// reads; small mutable arrays (U/GH/GIE/FE/GE/FP/CP) -> sc0sc1 uncached,
// lane-coalesced (row,b) access only.

#define DEVI static __device__ __forceinline__
typedef float f32x4 __attribute__((ext_vector_type(4)));

constexpr int ATTN_OFF = 786432;

// ws offsets (floats)
constexpr int OFF_HALL = 0;        // 65 x (768k,32b) h per step (k,b)
constexpr int OFF_U    = 1597440;  // (b,k) 32*768, uncached
constexpr int OFF_CALL = 1622016;  // 64 x (b,k) c_t, write-once cached
constexpr int OFF_HIST = 3194880;  // 64 x (b,o) hist_t, write-once cached
constexpr int OFF_WALL = 3981312;  // 64 x (b,o) w_i, write-once cached
constexpr int OFF_GH   = 4767744;  // (row,b) 2304*32, uncached
constexpr int OFF_GIE  = 4841472;  // (row,b) 2304*32, uncached
constexpr int OFF_FE   = 4915200;  // (row,b) 384*32, uncached
constexpr int OFF_GE   = 4927488;  // (row,b) 768*32, uncached
constexpr int OFF_FP   = 4952064;  // (row,b) 384*32, uncached
constexpr int OFF_CP   = 4964352;  // (row,b) 768*32, uncached
constexpr int OFF_GHM  = 4988928;  // Gh (768,768) = A_o F_h  read-only
constexpr int OFF_GWM  = 5578752;  // Gw (768,384) = A_o F_w  read-only
constexpr int OFF_GEM  = 5873664;  // Ge (768,384) = A_o F_e  read-only
constexpr int OFF_GB   = 6168576;  // 768 = A_o fc_b
constexpr int OFF_V1   = 6169344;  // M = sum|v|
constexpr int OFF_BAR  = 6169376;  // barrier, 1152 u32
// total ~6170528 floats = 24.7 MiB

DEVI float fast_tanh(float x) {
  float a = __builtin_fabsf(x);
  float e = __expf(-2.0f * a);
  float r = __fdividef(1.0f - e, 1.0f + e);
  return __builtin_copysignf(r, x);
}
DEVI float sigmoidf_(float x) {
  return __fdividef(1.0f, 1.0f + __expf(-x));
}

DEVI float nc_ld_f1(const float* p) {
  float r;
  asm volatile("global_load_dword %0, %1, off sc0 sc1\n\ts_waitcnt vmcnt(0)"
               : "=&v"(r) : "v"(p) : "memory");
  return r;
}
DEVI void nc_ld_f1x4(const float* p0, const float* p1, const float* p2, const float* p3,
                     float& r0, float& r1, float& r2, float& r3) {
  asm volatile(
      "global_load_dword %0, %4, off sc0 sc1\n\t"
      "global_load_dword %1, %5, off sc0 sc1\n\t"
      "global_load_dword %2, %6, off sc0 sc1\n\t"
      "global_load_dword %3, %7, off sc0 sc1\n\t"
      "s_waitcnt vmcnt(0)"
      : "=&v"(r0), "=&v"(r1), "=&v"(r2), "=&v"(r3)
      : "v"(p0), "v"(p1), "v"(p2), "v"(p3) : "memory");
}
DEVI void nc_st_f1(float* p, float v_) {
  asm volatile("global_store_dword %0, %1, off sc0 sc1" :: "v"(p), "v"(v_) : "memory");
}

// ---- relaxed-only grid barrier (no cache maintenance) ----
DEVI void gridbar(unsigned* bar) {
  asm volatile("s_waitcnt vmcnt(0)" ::: "memory");
  __syncthreads();
  if (threadIdx.x == 0) {
    unsigned* super = bar + 1024;
    unsigned* gen   = bar + 1056;
    unsigned g = __hip_atomic_load(gen, __ATOMIC_RELAXED, __HIP_MEMORY_SCOPE_AGENT);
    int grp = (int)(blockIdx.x >> 3);
    unsigned a = __hip_atomic_fetch_add(bar + grp * 32, 1u, __ATOMIC_RELAXED, __HIP_MEMORY_SCOPE_AGENT);
    bool released = false;
    if (a == 7u) {
      __hip_atomic_store(bar + grp * 32, 0u, __ATOMIC_RELAXED, __HIP_MEMORY_SCOPE_AGENT);
      unsigned s = __hip_atomic_fetch_add(super, 1u, __ATOMIC_RELAXED, __HIP_MEMORY_SCOPE_AGENT);
      if (s == 31u) {
        __hip_atomic_store(super, 0u, __ATOMIC_RELAXED, __HIP_MEMORY_SCOPE_AGENT);
        __hip_atomic_fetch_add(gen, 1u, __ATOMIC_RELAXED, __HIP_MEMORY_SCOPE_AGENT);
        released = true;
      }
    }
    if (!released) {
      while (__hip_atomic_load(gen, __ATOMIC_RELAXED, __HIP_MEMORY_SCOPE_AGENT) == g) {
        __builtin_amdgcn_s_sleep(1);
      }
    }
  }
  __syncthreads();
}

// ---------- precompute kernel: Gh/Gw/Ge/gb ----------
__global__ __launch_bounds__(256) void kprepG(const float* __restrict__ attn_W,
                                              const float* __restrict__ fcW,
                                              const float* __restrict__ fcb,
                                              float* __restrict__ ws) {
  int bid = blockIdx.x, tid = threadIdx.x;
  if (bid < 288) {
    int rt = bid / 6, kt = bid % 6;
    int r0 = rt * 16;
    int kg = kt * 256 + tid;
    float acc[16];
#pragma unroll
    for (int q = 0; q < 16; ++q) acc[q] = 0.f;
    for (int o = 0; o < 384; ++o) {
      float f = fcW[o * 1536 + kg];
#pragma unroll
      for (int q = 0; q < 16; ++q)
        acc[q] = fmaf(attn_W[(r0 + q) * 1152 + 768 + o], f, acc[q]);
    }
#pragma unroll
    for (int q = 0; q < 16; ++q) {
      int r = r0 + q;
      if (kg < 768)       ws[OFF_GHM + r * 768 + kg] = acc[q];
      else if (kg < 1152) ws[OFF_GWM + r * 384 + (kg - 768)] = acc[q];
      else                ws[OFF_GEM + r * 384 + (kg - 1152)] = acc[q];
    }
  } else {
    for (int r = tid; r < 768; r += 256) {
      float a = 0.f;
      for (int o = 0; o < 384; ++o) a = fmaf(attn_W[r * 1152 + 768 + o], fcb[o], a);
      ws[OFF_GB + r] = a;
    }
  }
}

// ---------- prep kernel ----------
__global__ __launch_bounds__(256) void kprep0(const float* __restrict__ hidden,
                                              const float* __restrict__ vW,
                                              float* __restrict__ ws) {
  int bid = blockIdx.x, tid = threadIdx.x;
  int gtid = bid * 256 + tid;
  if (gtid < 24576) {
    int k = gtid >> 5, b = gtid & 31;
    ws[OFF_HALL + gtid] = hidden[b * 768 + k];  // transpose to (k,b)
    ws[OFF_CALL + gtid] = 0.f;                  // c_0 = 0 (b,k)
  }
  if (gtid < 12288) ws[OFF_HIST + gtid] = 0.f;  // hist_0 = 0
  if (gtid < 1152) ((unsigned*)(ws + OFF_BAR))[gtid] = 0u;
  if (bid == 0) {
    __shared__ float vred[256];
    float a = 0.f;
    for (int k = tid; k < 768; k += 256) a += __builtin_fabsf(vW[k]);
    vred[tid] = a;
    __syncthreads();
    for (int s2 = 128; s2 > 0; s2 >>= 1) {
      if (tid < s2) vred[tid] += vred[tid + s2];
      __syncthreads();
    }
    if (tid == 0) ws[OFF_V1] = vred[0];
  }
}

// ---------- main persistent cooperative kernel ----------
__global__ void __launch_bounds__(1024)
kmain(const int* __restrict__ target, const float* __restrict__ emb,
      const float* __restrict__ attn_W, const float* __restrict__ attn_b,
      const float* __restrict__ vW,
      const float* __restrict__ Wih, const float* __restrict__ Whh,
      const float* __restrict__ bih, const float* __restrict__ bhh,
      const float* __restrict__ fcW, const float* __restrict__ fcb,
      float* __restrict__ outp, float* __restrict__ ws) {
  const int bid = blockIdx.x, tid = threadIdx.x;
  const int wv = tid >> 6, lane = tid & 63;
  const int b32 = lane & 31, kh = lane >> 5;
  // XCD-major virtual block id: blocks with same (bid&7) share an XCD L2.
  const int vb = ((bid & 7) << 5) | (bid >> 3);
  const int xcd = vb >> 5, slot = vb & 31;
  unsigned* bar = (unsigned*)(ws + OFF_BAR);

  __shared__ __align__(16) float smem[13312];

  const float Mv = ws[OFF_V1];

  for (int i = 0; i < 64; ++i) {
    // ============ Phase A: u, gh, c_i, hist_i (4224 rows = 1056 groups, K=768) ====
    {
      float* part_ = smem;         // 4096
      float* stage = smem + 4096;  // 256
      float xr[24];
      const float* hb = ws + OFF_HALL + i * 24576 + b32;  // cached (k,b), lanes->b
      const int k0 = wv * 48 + kh * 24;
#pragma unroll
      for (int q = 0; q < 24; ++q) xr[q] = hb[(k0 + q) * 32];

      const int gb = (vb * 1056) >> 8, geE = ((vb + 1) * 1056) >> 8;
      const int nsw = (geE - gb + 1) >> 1;
      for (int sw = 0; sw < nsw; ++sw) {
        const int g0 = gb + sw * 2;
        float a[8];
#pragma unroll
        for (int q = 0; q < 8; ++q) a[q] = 0.f;
#pragma unroll
        for (int gg = 0; gg < 2; ++gg) {
          int g = g0 + gg;
          if (g < geE && !(i == 0 && g >= 768)) {
            const float* Wb; int ld;
            if (g < 192)      { Wb = attn_W + (g * 4) * 1152;               ld = 1152; }
            else if (g < 768) { Wb = Whh + ((g - 192) * 4) * 768;           ld = 768;  }
            else if (g < 960) { Wb = ws + OFF_GHM + ((g - 768) * 4) * 768;  ld = 768;  }
            else              { Wb = fcW + ((g - 960) * 4) * 1536;          ld = 1536; }
            const float* wp = Wb + k0;
#pragma unroll
            for (int r = 0; r < 4; ++r) {
              float acc = 0.f;
#pragma unroll
              for (int q = 0; q < 6; ++q) {
                f32x4 wq = *(const f32x4*)(wp + r * ld + q * 4);
                acc = fmaf(wq[0], xr[q * 4 + 0], acc);
                acc = fmaf(wq[1], xr[q * 4 + 1], acc);
                acc = fmaf(wq[2], xr[q * 4 + 2], acc);
                acc = fmaf(wq[3], xr[q * 4 + 3], acc);
              }
              a[gg * 4 + r] = acc;
            }
          }
        }
#pragma unroll
        for (int r8 = 0; r8 < 8; ++r8) a[r8] += __shfl_xor(a[r8], 32);
        if (kh == 0) {
#pragma unroll
          for (int r8 = 0; r8 < 8; ++r8) part_[wv * 256 + r8 * 32 + b32] = a[r8];
        }
        __syncthreads();
        // pass1: finalize sums; direct coalesced store for GH; stage U/C/HIST
        if (tid < 256) {
          int rr = tid >> 5, bb = tid & 31;
          int g2 = g0 + (rr >> 2);
          int row = g0 * 4 + rr;
          if (g2 < geE && !(i == 0 && row >= 3072)) {
            float sum = 0.f;
#pragma unroll
            for (int wvv = 0; wvv < 16; ++wvv) sum += part_[wvv * 256 + tid];
            if (row < 768) {
              stage[rr * 32 + bb] = sum + attn_b[row];
            } else if (row < 3072) {
              nc_st_f1(ws + OFF_GH + (row - 768) * 32 + bb, sum + bhh[row - 768]);
            } else if (row < 3840) {
              stage[rr * 32 + bb] = sum + nc_ld_f1(ws + OFF_CP + (row - 3072) * 32 + bb);
            } else {
              stage[rr * 32 + bb] = sum + nc_ld_f1(ws + OFF_FP + (row - 3840) * 32 + bb);
            }
          }
        }
        __syncthreads();
        // pass2: (bb, rl) mapping -> lanes walk rows (32B-granule coalesced)
        if (tid < 256) {
          int bb = tid >> 3, rl = tid & 7;
          int g2 = g0 + (rl >> 2);
          int row = g0 * 4 + rl;
          if (g2 < geE) {
            float v = stage[rl * 32 + bb];
            if (row < 768) {
              nc_st_f1(ws + OFF_U + bb * 768 + row, v);
            } else if (row >= 3840) {
              if (i > 0) nc_st_f1(ws + OFF_HIST + i * 12288 + bb * 384 + (row - 3840), v);
            } else if (row >= 3072) {
              if (i > 0) nc_st_f1(ws + OFF_CALL + i * 24576 + bb * 768 + (row - 3072), v);
            }
          }
        }
        __syncthreads();
      }
    }
    gridbar(bar);

    // ============ Phase B: attention (32 blocks, one per b) | gie/fe/ge (224) ====
    if (slot < 4) {
      const int bb = xcd * 4 + (vb & 3);
      float* u_s  = smem;          // 768
      float* p_l  = smem + 768;    // 64
      float* d_l  = smem + 832;    // 1
      float* wred = smem + 848;    // 768
      if (tid < 768) u_s[tid] = nc_ld_f1(ws + OFF_U + bb * 768 + tid);
      if (tid < 64) p_l[tid] = 0.f;
      __syncthreads();
      const int tl = tid >> 5, kc = tid & 31;
      float u_r[24], v_r[24];
#pragma unroll
      for (int q = 0; q < 24; ++q) {
        u_r[q] = u_s[kc * 24 + q];
        v_r[q] = vW[kc * 24 + q];
      }
#pragma unroll
      for (int rr2 = 0; rr2 < 2; ++rr2) {
        int t = rr2 * 32 + tl;
        float s = 0.f;
        if (t <= i) {
          const float* cb = ws + OFF_CALL + t * 24576 + bb * 768 + kc * 24;  // cached
#pragma unroll
          for (int q6 = 0; q6 < 6; ++q6) {
            f32x4 cq = *(const f32x4*)(cb + q6 * 4);
#pragma unroll
            for (int e = 0; e < 4; ++e)
              s = fmaf(fast_tanh(u_r[q6 * 4 + e] + cq[e]), v_r[q6 * 4 + e], s);
          }
        }
#pragma unroll
        for (int d2 = 16; d2 >= 1; d2 >>= 1) s += __shfl_xor(s, d2);
        if (kc == 0 && t <= i) p_l[t] = __expf(s - Mv);
      }
      __syncthreads();
      if (tid == 0) {
        float D = 0.f;
        for (int t = 0; t <= i; ++t) D += p_l[t];
        d_l[0] = __fdividef(1.0f, D);
      }
      __syncthreads();
      float dinv = d_l[0];
      if (tid <= i)
        outp[ATTN_OFF + bb * 2080 + (i * (i + 1)) / 2 + tid] = p_l[tid] * dinv;
      if (tid < 768) {
        int hf = tid >= 384 ? 1 : 0;
        int o = tid - hf * 384;
        float acc = 0.f;
        for (int t = hf; t <= i; t += 2)
          acc = fmaf(p_l[t], ws[OFF_HIST + t * 12288 + bb * 384 + o], acc);  // cached
        wred[tid] = acc;
      }
      __syncthreads();
      if (tid < 384)
        nc_st_f1(ws + OFF_WALL + i * 12288 + bb * 384 + tid,
                 (wred[tid] + wred[384 + tid]) * dinv);
    } else {
      float* part_ = smem;  // 2048
      const int lb = slot - 4;
      const int gb2 = xcd * 108 + (lb * 108) / 28;
      const int ge2 = xcd * 108 + ((lb + 1) * 108) / 28;
      const int gl = wv >> 2, kq = wv & 3;
      const int tok = target[b32 * 65 + i];
      const float* xe = emb + tok * 384 + kq * 96 + kh * 48;
      const int nsw2 = (ge2 - gb2 + 3) >> 2;
      for (int sw = 0; sw < nsw2; ++sw) {
        int g = gb2 + sw * 4 + gl;
        float a0 = 0.f, a1 = 0.f, a2 = 0.f, a3 = 0.f;
        if (g < ge2) {
          const float* Wb; int ld;
          if (g < 576)      { Wb = Wih + (g * 4) * 768;                    ld = 768;  }
          else if (g < 672) { Wb = fcW + ((g - 576) * 4) * 1536 + 1152;    ld = 1536; }
          else              { Wb = ws + OFF_GEM + ((g - 672) * 4) * 384;   ld = 384;  }
          const float* wp = Wb + kq * 96 + kh * 48;
#pragma unroll 6
          for (int q = 0; q < 12; ++q) {
            f32x4 xq = *(const f32x4*)(xe + q * 4);
            f32x4 w0 = *(const f32x4*)(wp + q * 4);
            f32x4 w1 = *(const f32x4*)(wp + ld + q * 4);
            f32x4 w2 = *(const f32x4*)(wp + 2 * ld + q * 4);
            f32x4 w3 = *(const f32x4*)(wp + 3 * ld + q * 4);
            a0 = fmaf(w0[0], xq[0], a0); a0 = fmaf(w0[1], xq[1], a0);
            a0 = fmaf(w0[2], xq[2], a0); a0 = fmaf(w0[3], xq[3], a0);
            a1 = fmaf(w1[0], xq[0], a1); a1 = fmaf(w1[1], xq[1], a1);
            a1 = fmaf(w1[2], xq[2], a1); a1 = fmaf(w1[3], xq[3], a1);
            a2 = fmaf(w2[0], xq[0], a2); a2 = fmaf(w2[1], xq[1], a2);
            a2 = fmaf(w2[2], xq[2], a2); a2 = fmaf(w2[3], xq[3], a2);
            a3 = fmaf(w3[0], xq[0], a3); a3 = fmaf(w3[1], xq[1], a3);
            a3 = fmaf(w3[2], xq[2], a3); a3 = fmaf(w3[3], xq[3], a3);
          }
        }
        a0 += __shfl_xor(a0, 32); a1 += __shfl_xor(a1, 32);
        a2 += __shfl_xor(a2, 32); a3 += __shfl_xor(a3, 32);
        if (kh == 0) {
          float* pp = part_ + ((gl * 4 + kq) * 4) * 32 + b32;
          pp[0] = a0; pp[32] = a1; pp[64] = a2; pp[96] = a3;
        }
        __syncthreads();
        if (tid < 512) {
          int gl2 = tid >> 7, rr = (tid >> 5) & 3, bb = tid & 31;
          int g2 = gb2 + sw * 4 + gl2;
          if (g2 < ge2) {
            float sum = part_[((gl2 * 4 + 0) * 4 + rr) * 32 + bb]
                      + part_[((gl2 * 4 + 1) * 4 + rr) * 32 + bb]
                      + part_[((gl2 * 4 + 2) * 4 + rr) * 32 + bb]
                      + part_[((gl2 * 4 + 3) * 4 + rr) * 32 + bb];
            int row = g2 * 4 + rr;
            if (row < 2304) {
              nc_st_f1(ws + OFF_GIE + row * 32 + bb, sum + bih[row]);
            } else if (row < 2688) {
              nc_st_f1(ws + OFF_FE + (row - 2304) * 32 + bb, sum + fcb[row - 2304]);
            } else {
              nc_st_f1(ws + OFF_GE + (row - 2688) * 32 + bb, sum + ws[OFF_GB + (row - 2688)]);
            }
          }
        }
        __syncthreads();
      }
    }
    gridbar(bar);

    // ============ Phase C: giw, fpart/cpart, gates ====
    {
      float* w_lds   = smem;           // 32*388 = 12416
      float* g_lds   = smem + 12416;   // 576
      float* giw_lds = smem + 12992;   // 288
      {
        int b = tid >> 5, c = tid & 31;
        const float* src = ws + OFF_WALL + i * 12288 + tid * 12;  // cached coalesced
        float* dst = w_lds + b * 388 + c * 12;
#pragma unroll
        for (int e = 0; e < 12; ++e) dst[e] = src[e];
      }
      __syncthreads();
      if (wv < 9) {
        // giw: Wih[:,384:768] . w  — 3 j rows x 3 gates per block
        int jl = wv / 3, gg = wv % 3;
        int grow = vb * 3 + jl + gg * 768;
        const float* wp = Wih + grow * 768 + 384 + kh * 192;
        const float* xp = w_lds + b32 * 388 + kh * 192;
        float acc = 0.f;
#pragma unroll 8
        for (int q = 0; q < 48; ++q) {
          f32x4 wq4 = *(const f32x4*)(wp + q * 4);
          f32x4 xq4 = *(const f32x4*)(xp + q * 4);
          acc = fmaf(wq4[0], xq4[0], acc); acc = fmaf(wq4[1], xq4[1], acc);
          acc = fmaf(wq4[2], xq4[2], acc); acc = fmaf(wq4[3], xq4[3], acc);
        }
        acc += __shfl_xor(acc, 32);
        if (kh == 0) giw_lds[(jl * 3 + gg) * 32 + b32] = acc;
      } else if (wv < 14) {
        // fpart/cpart: 1152 rows, XCD slice 144, per-block 4..5 rows
        int rb = xcd * 144 + ((slot * 144) >> 5);
        int re = xcd * 144 + (((slot + 1) * 144) >> 5);
        int r = rb + (wv - 9);
        if (r < re) {
          const float* wp; const float* addp; float* dst;
          if (r < 384) {
            wp = fcW + r * 1536 + 768;
            addp = ws + OFF_FE + r * 32 + b32;
            dst = ws + OFF_FP + r * 32 + b32;
          } else {
            wp = ws + OFF_GWM + (r - 384) * 384;
            addp = ws + OFF_GE + (r - 384) * 32 + b32;
            dst = ws + OFF_CP + (r - 384) * 32 + b32;
          }
          const float* wpp = wp + kh * 192;
          const float* xp = w_lds + b32 * 388 + kh * 192;
          float acc = 0.f;
#pragma unroll 8
          for (int q = 0; q < 48; ++q) {
            f32x4 wq4 = *(const f32x4*)(wpp + q * 4);
            f32x4 xq4 = *(const f32x4*)(xp + q * 4);
            acc = fmaf(wq4[0], xq4[0], acc); acc = fmaf(wq4[1], xq4[1], acc);
            acc = fmaf(wq4[2], xq4[2], acc); acc = fmaf(wq4[3], xq4[3], acc);
          }
          acc += __shfl_xor(acc, 32);
          if (kh == 0) nc_st_f1(dst, acc + nc_ld_f1(addp));
        }
      } else {
        // stage GIE/GH rows for gates (coalesced uncached, batched)
        int base = tid - 896;  // 0..127
        const float* pp[4];
#pragma unroll
        for (int q = 0; q < 4; ++q) {
          int idx = base + q * 128;
          int a1 = idx >= 288 ? 1 : 0;
          int ridx = idx - a1 * 288;
          int rg = ridx >> 5, bbs = ridx & 31;
          int r = vb * 3 + (rg % 3) + (rg / 3) * 768;
          pp[q] = ws + (a1 ? OFF_GH : OFF_GIE) + r * 32 + bbs;
        }
        float v0, v1, v2, v3;
        nc_ld_f1x4(pp[0], pp[1], pp[2], pp[3], v0, v1, v2, v3);
        g_lds[base] = v0; g_lds[base + 128] = v1;
        g_lds[base + 256] = v2; g_lds[base + 384] = v3;
        if (base < 64) {
          int idx = base + 512;
          int ridx = idx - 288;  // idx >= 512 -> GH half
          int rg = ridx >> 5, bbs = ridx & 31;
          int r = vb * 3 + (rg % 3) + (rg / 3) * 768;
          g_lds[idx] = nc_ld_f1(ws + OFF_GH + r * 32 + bbs);
        }
      }
      __syncthreads();
      // gates
      if (tid < 96) {
        int jl = tid >> 5, bb = tid & 31;
        int j = vb * 3 + jl;
        float gi_r = g_lds[jl * 32 + bb];
        float gi_z = g_lds[(3 + jl) * 32 + bb];
        float gi_n = g_lds[(6 + jl) * 32 + bb];
        float gh_r = g_lds[288 + jl * 32 + bb];
        float gh_z = g_lds[288 + (3 + jl) * 32 + bb];
        float gh_n = g_lds[288 + (6 + jl) * 32 + bb];
        float giw_r = giw_lds[(jl * 3 + 0) * 32 + bb];
        float giw_z = giw_lds[(jl * 3 + 1) * 32 + bb];
        float giw_n = giw_lds[(jl * 3 + 2) * 32 + bb];
        float hold = ws[OFF_HALL + i * 24576 + j * 32 + bb];  // cached
        float r_ = sigmoidf_(gi_r + giw_r + gh_r);
        float z_ = sigmoidf_(gi_z + giw_z + gh_z);
        float n_ = fast_tanh(fmaf(r_, gh_n, gi_n + giw_n));
        nc_st_f1(ws + OFF_HALL + (i + 1) * 24576 + j * 32 + bb,
                 (1.0f - z_) * n_ + z_ * hold);
      }
    }
    gridbar(bar);
  }

  // ============ epilogue: out_63 = F_h h_64 + fp_63 (384 rows, 3 blocks/XCD) ====
  if (slot < 3) {
    int o = xcd * 48 + slot * 16 + wv;
    const float* hcol = ws + OFF_HALL + 64 * 24576 + b32;  // cached (k,b)
    const float* wrow = fcW + o * 1536 + kh * 384;
    float acc = 0.f;
#pragma unroll 4
    for (int q = 0; q < 96; ++q) {
      f32x4 wq = *(const f32x4*)(wrow + q * 4);
      int k = kh * 384 + q * 4;
      acc = fmaf(wq[0], hcol[k * 32], acc);
      acc = fmaf(wq[1], hcol[(k + 1) * 32], acc);
      acc = fmaf(wq[2], hcol[(k + 2) * 32], acc);
      acc = fmaf(wq[3], hcol[(k + 3) * 32], acc);
    }
    acc += __shfl_xor(acc, 32);
    if (kh == 0) {
      float fp = nc_ld_f1(ws + OFF_FP + o * 32 + b32);
      outp[b32 * 24576 + o * 64 + 63] = acc + fp;
    }
  }
  // ============ final transpose: outputs[b][o][t] for t=0..62 from HIST ====
  if (tid < 48) {
    int pair = vb * 48 + tid;
    int b = pair / 384, o = pair - b * 384;
    const float* src = ws + OFF_HIST + b * 384 + o;
    float* dst = outp + b * 24576 + o * 64;
#pragma unroll 7
    for (int t = 0; t < 63; ++t) dst[t] = src[(t + 1) * 12288];
  }
}

extern "C" void kernel_launch(void* const* d_in, const int* in_sizes, int n_in,
                              void* d_out, int out_size, void* d_ws, size_t ws_size,
                              hipStream_t stream) {
  const int*   target = (const int*)d_in[0];
  const float* hidden = (const float*)d_in[1];
  // d_in[2] = teacher_forcing_ratio (== 1, deterministic path)
  const float* emb    = (const float*)d_in[3];
  const float* attn_W = (const float*)d_in[4];
  const float* attn_b = (const float*)d_in[5];
  const float* vW     = (const float*)d_in[6];
  const float* Wih    = (const float*)d_in[7];
  const float* Whh    = (const float*)d_in[8];
  const float* bih    = (const float*)d_in[9];
  const float* bhh    = (const float*)d_in[10];
  const float* fcW    = (const float*)d_in[11];
  const float* fcb    = (const float*)d_in[12];
  float* outp = (float*)d_out;
  float* ws   = (float*)d_ws;

  kprepG<<<289, 256, 0, stream>>>(attn_W, fcW, fcb, ws);
  kprep0<<<256, 256, 0, stream>>>(hidden, vW, ws);

  void* args[] = {(void*)&target, (void*)&emb, (void*)&attn_W, (void*)&attn_b,
                  (void*)&vW, (void*)&Wih, (void*)&Whh, (void*)&bih, (void*)&bhh,
                  (void*)&fcW, (void*)&fcb, (void*)&outp, (void*)&ws};
  hipLaunchCooperativeKernel((const void*)kmain, dim3(256), dim3(1024), args, 0, stream);
}